// Round 5
// baseline (198.731 us; speedup 1.0000x reference)
//
#include <hip/hip_runtime.h>
#include <hip/hip_bf16.h>
#include <math.h>

// Problem constants (B=4096, D=128, T=0.5 -> 1/T = 2)
#define BB       4096
#define N2       8192          // 2B rows of z
#define DIMS     128
#define WAVES    4
#define ROWTILES 4             // 16-row MFMA tiles per wave
#define ROWS_PER_WAVE   64     // ROWTILES * 16
#define ROWS_PER_BLOCK  256    // WAVES * ROWS_PER_WAVE
#define COLS_PER_BLOCK  128
#define COL_SPLIT       (N2 / COLS_PER_BLOCK)    // 64
#define GRID            ((N2 / ROWS_PER_BLOCK) * COL_SPLIT)  // 32*64 = 2048

// z rows pre-scaled by ZSCALE so the MFMA dot yields sim * 2*log2(e),
// i.e. exp(sim/T) = exp2(acc). ZSCALE^2 = 2*log2(e) = 2.8853900818.
#define ZSCALE   1.6986436f
// diagonal term exp(2*|z_r|^2) ~= e^2 — included in denom, subtracted later.
#define DIAG_E2  7.38905609893065f

typedef __attribute__((ext_vector_type(8))) short short8;   // 8 x bf16 (4 VGPRs)
typedef __attribute__((ext_vector_type(4))) float float4v;  // MFMA C/D

// ---------------------------------------------------------------------------
// Kernel 1: normalize rows (fp32), positives (fp32), write z bf16 * ZSCALE.
// One wave per row-pair r: emb_i[r] -> z[r], emb_j[r] -> z[r+B].
// ---------------------------------------------------------------------------
__global__ __launch_bounds__(256) void norm_kernel(
    const float* __restrict__ emb_i, const float* __restrict__ emb_j,
    __hip_bfloat16* __restrict__ z, float* __restrict__ pos) {
  int gw   = (blockIdx.x * blockDim.x + threadIdx.x) >> 6;  // row pair
  int lane = threadIdx.x & 63;
  if (gw >= BB) return;

  const float2* ei = (const float2*)(emb_i + (size_t)gw * DIMS);
  const float2* ej = (const float2*)(emb_j + (size_t)gw * DIMS);
  float2 a = ei[lane];
  float2 b = ej[lane];

  float sa = a.x * a.x + a.y * a.y;
  float sb = b.x * b.x + b.y * b.y;
  #pragma unroll
  for (int m = 32; m; m >>= 1) {
    sa += __shfl_xor(sa, m, 64);
    sb += __shfl_xor(sb, m, 64);
  }
  float inva = 1.0f / fmaxf(sqrtf(sa), 1e-12f);
  float invb = 1.0f / fmaxf(sqrtf(sb), 1e-12f);

  float zi0 = a.x * inva, zi1 = a.y * inva;
  float zj0 = b.x * invb, zj1 = b.y * invb;

  // positive pair dot in unscaled fp32 (matches reference's fp32 einsum)
  float p = zi0 * zj0 + zi1 * zj1;
  #pragma unroll
  for (int m = 32; m; m >>= 1) p += __shfl_xor(p, m, 64);
  if (lane == 0) pos[gw] = p;

  __hip_bfloat162* zr_i = (__hip_bfloat162*)(z + (size_t)gw * DIMS);
  __hip_bfloat162* zr_j = (__hip_bfloat162*)(z + (size_t)(gw + BB) * DIMS);
  __hip_bfloat162 vi, vj;
  vi.x = __float2bfloat16(zi0 * ZSCALE); vi.y = __float2bfloat16(zi1 * ZSCALE);
  vj.x = __float2bfloat16(zj0 * ZSCALE); vj.y = __float2bfloat16(zj1 * ZSCALE);
  zr_i[lane] = vi;
  zr_j[lane] = vj;
}

// ---------------------------------------------------------------------------
// Kernel 2: fused sim-GEMM + exp2 + row-sum -> PARTIAL STORES (no atomics).
// Identical compute structure to R4 (4 blocks/CU, one staging barrier,
// XOR-swizzled 32KB B-panel, 64 A-rows pinned per wave). Difference: the
// per-row partial sums go to partial[colBlk][row] via an LDS transpose and
// ONE coalesced 1KB store per block. No RMW, no cross-XCD line ping-pong.
// MFMA 16x16x32 bf16: A[m=lane&15][k=quad*8+j], B[k=quad*8+j][n=lane&15],
// C: col=lane&15, row=quad*4+reg (HW-verified layouts).
// ---------------------------------------------------------------------------
__global__ __launch_bounds__(256, 4) void simloss_main(
    const __hip_bfloat16* __restrict__ z, float* __restrict__ partial) {
  const int blk     = blockIdx.x;
  const int rowBase = (blk >> 6) * ROWS_PER_BLOCK;   // 32 row-blocks
  const int colBlk  = blk & 63;
  const int colBase = colBlk * COLS_PER_BLOCK;       // 64 col-blocks
  const int tid  = threadIdx.x;
  const int wave = tid >> 6;
  const int lane = tid & 63;
  const int lr   = lane & 15;          // A-row / B-col / C-col within tile
  const int quad = lane >> 4;          // k-group for A/B, row-group for C

  __shared__ short lds[COLS_PER_BLOCK * DIMS];  // 32768 B

  const ushort* zp = (const ushort*)z;

  // ---- A fragments first (in flight during staging): 64 rows/wave. ----
  short8 afrag[ROWTILES][4];
  #pragma unroll
  for (int rt = 0; rt < ROWTILES; rt++) {
    const int arow = rowBase + wave * ROWS_PER_WAVE + rt * 16 + lr;
    const short8* ap = (const short8*)(zp + (size_t)arow * DIMS + quad * 8);
    afrag[rt][0] = ap[0];
    afrag[rt][1] = ap[4];   // +32 shorts (k += 32)
    afrag[rt][2] = ap[8];
    afrag[rt][3] = ap[12];
  }

  // ---- Stage the B-panel: 2048 short8, 8 per thread, swizzled. ----
  {
    const short8* src = (const short8*)(zp + (size_t)colBase * DIMS);
    #pragma unroll
    for (int i = 0; i < 8; i++) {
      int idx  = tid + 256 * i;          // linear short8 index
      int row  = idx >> 4;               // 16 short8 per 128-short row
      int col8 = idx & 15;
      int sw   = col8 ^ (row & 15);      // XOR swizzle
      *(short8*)&lds[row * DIMS + sw * 8] = src[idx];
    }
  }
  __syncthreads();

  float rowsum[ROWTILES][4];
  #pragma unroll
  for (int rt = 0; rt < ROWTILES; rt++)
    #pragma unroll
    for (int r = 0; r < 4; r++) rowsum[rt][r] = 0.0f;

  // ---- 8 column tiles of 16; no barriers inside. ----
  #pragma unroll
  for (int t = 0; t < 8; t++) {
    const int row = t * 16 + lr;                 // B-panel row (= z column)
    short8 bkk[4];
    #pragma unroll
    for (int kk = 0; kk < 4; kk++) {
      int col8 = (kk * 4 + quad) ^ lr;           // swizzled k-group position
      bkk[kk] = *(const short8*)&lds[row * DIMS + col8 * 8];
    }
    #pragma unroll
    for (int rt = 0; rt < ROWTILES; rt++) {
      float4v acc = {0.0f, 0.0f, 0.0f, 0.0f};
      acc = __builtin_amdgcn_mfma_f32_16x16x32_bf16(afrag[rt][0], bkk[0], acc, 0, 0, 0);
      acc = __builtin_amdgcn_mfma_f32_16x16x32_bf16(afrag[rt][1], bkk[1], acc, 0, 0, 0);
      acc = __builtin_amdgcn_mfma_f32_16x16x32_bf16(afrag[rt][2], bkk[2], acc, 0, 0, 0);
      acc = __builtin_amdgcn_mfma_f32_16x16x32_bf16(afrag[rt][3], bkk[3], acc, 0, 0, 0);
      // exp(sim/T) = exp2(acc) thanks to ZSCALE pre-scaling.
      #pragma unroll
      for (int r = 0; r < 4; r++)
        rowsum[rt][r] += __builtin_amdgcn_exp2f(acc[r]);
    }
  }

  // ---- Reduce across the 16 lanes of each quad. ----
  #pragma unroll
  for (int m = 1; m < 16; m <<= 1) {
    #pragma unroll
    for (int rt = 0; rt < ROWTILES; rt++)
      #pragma unroll
      for (int r = 0; r < 4; r++)
        rowsum[rt][r] += __shfl_xor(rowsum[rt][r], m, 64);
  }

  // ---- LDS transpose -> one coalesced 1KB store (rows contiguous). ----
  __syncthreads();                       // all LDS B-panel reads done
  float* ldsf = (float*)lds;
  if (lr == 0) {
    #pragma unroll
    for (int rt = 0; rt < ROWTILES; rt++)
      #pragma unroll
      for (int r = 0; r < 4; r++)
        ldsf[wave * ROWS_PER_WAVE + rt * 16 + quad * 4 + r] = rowsum[rt][r];
  }
  __syncthreads();
  partial[(size_t)colBlk * N2 + rowBase + tid] = ldsf[tid];
}

// ---------------------------------------------------------------------------
// Kernel 3: per-row reduction over the 64 column partials + log + positives.
// 32 blocks x 256 threads; thread owns one row; all loads coalesced
// (consecutive threads -> consecutive rows within each colBlk plane).
// Block-level double reduction -> blocksum[blockIdx].
// ---------------------------------------------------------------------------
__global__ __launch_bounds__(256) void reduce_rows(
    const float* __restrict__ partial, const float* __restrict__ pos,
    double* __restrict__ blocksum) {
  const int row = blockIdx.x * 256 + threadIdx.x;
  float d = 0.0f;
  #pragma unroll 8
  for (int c = 0; c < COL_SPLIT; c++)
    d += partial[(size_t)c * N2 + row];
  double v = (double)(logf(d - DIAG_E2) - 2.0f * pos[row & (BB - 1)]);

  __shared__ double sred[256];
  int tid = threadIdx.x;
  sred[tid] = v;
  __syncthreads();
  for (int s = 128; s; s >>= 1) {
    if (tid < s) sred[tid] += sred[tid + s];
    __syncthreads();
  }
  if (tid == 0) blocksum[blockIdx.x] = sred[0];
}

// ---------------------------------------------------------------------------
// Kernel 4: final scalar: loss = sum(blocksum) / 2B.
// ---------------------------------------------------------------------------
__global__ __launch_bounds__(64) void final_reduce(
    const double* __restrict__ blocksum, float* __restrict__ out) {
  int lane = threadIdx.x;
  double v = (lane < 32) ? blocksum[lane] : 0.0;
  #pragma unroll
  for (int m = 32; m; m >>= 1) v += __shfl_xor(v, m, 64);
  if (lane == 0) out[0] = (float)(v / (double)N2);
}

// ---------------------------------------------------------------------------
extern "C" void kernel_launch(void* const* d_in, const int* in_sizes, int n_in,
                              void* d_out, int out_size, void* d_ws, size_t ws_size,
                              hipStream_t stream) {
  const float* emb_i = (const float*)d_in[0];
  const float* emb_j = (const float*)d_in[1];

  // workspace layout
  __hip_bfloat16* z = (__hip_bfloat16*)d_ws;                       // 2 MiB
  float*  pos      = (float*)((char*)d_ws + (size_t)N2 * DIMS * 2); // 4096 f32
  float*  partial  = (float*)((char*)pos + BB * sizeof(float));     // 64*8192 f32 = 2 MiB
  double* blocksum = (double*)((char*)partial + (size_t)COL_SPLIT * N2 * sizeof(float));

  norm_kernel<<<BB / 4, 256, 0, stream>>>(emb_i, emb_j, z, pos);
  simloss_main<<<GRID, 256, 0, stream>>>(z, partial);
  reduce_rows<<<N2 / 256, 256, 0, stream>>>(partial, pos, blocksum);
  final_reduce<<<1, 64, 0, stream>>>(blocksum, (float*)d_out);
}

// Round 6
// 124.663 us; speedup vs baseline: 1.5941x; 1.5941x over previous
//
#include <hip/hip_runtime.h>
#include <hip/hip_bf16.h>
#include <math.h>

// Problem constants (B=4096, D=128, T=0.5 -> 1/T = 2)
#define BB       4096
#define N2       8192          // 2B rows of z
#define DIMS     128
#define WAVES    4
#define ROWTILES 4             // 16-row MFMA tiles per wave
#define ROWS_PER_WAVE   64     // ROWTILES * 16
#define ROWS_PER_BLOCK  256    // WAVES * ROWS_PER_WAVE
#define COL_SPLIT       16
#define COLS_PER_BLOCK  (N2 / COL_SPLIT)   // 512
#define CHUNK    64            // columns staged in LDS per iteration
#define LDS_PAD  8             // bf16 pad per row: breaks 256B-stride conflicts
#define LDS_ROWW (DIMS + LDS_PAD)  // 136 shorts = 272 B

// z rows pre-scaled by ZSCALE so the MFMA dot yields sim * 2*log2(e),
// i.e. exp(sim/T) = exp2(acc). ZSCALE^2 = 2*log2(e) = 2.8853900818.
#define ZSCALE   1.6986436f
// diagonal term exp(2*|z_r|^2) ~= e^2 — included in denom, subtracted in finalize.
#define DIAG_E2  7.38905609893065f

typedef __attribute__((ext_vector_type(8))) short short8;   // 8 x bf16 (4 VGPRs)
typedef __attribute__((ext_vector_type(4))) float float4v;  // MFMA C/D

// ---------------------------------------------------------------------------
// Kernel 1: normalize rows (fp32), positives (fp32), write z bf16 * ZSCALE.
// Also zeroes denom (blocks 0..31). One wave per row-pair r.
// ---------------------------------------------------------------------------
__global__ __launch_bounds__(256) void norm_kernel(
    const float* __restrict__ emb_i, const float* __restrict__ emb_j,
    __hip_bfloat16* __restrict__ z, float* __restrict__ pos,
    float* __restrict__ denom) {
  if (blockIdx.x < N2 / 256) denom[blockIdx.x * 256 + threadIdx.x] = 0.0f;

  int gw   = (blockIdx.x * blockDim.x + threadIdx.x) >> 6;  // row pair
  int lane = threadIdx.x & 63;
  if (gw >= BB) return;

  const float2* ei = (const float2*)(emb_i + (size_t)gw * DIMS);
  const float2* ej = (const float2*)(emb_j + (size_t)gw * DIMS);
  float2 a = ei[lane];
  float2 b = ej[lane];

  float sa = a.x * a.x + a.y * a.y;
  float sb = b.x * b.x + b.y * b.y;
  #pragma unroll
  for (int m = 32; m; m >>= 1) {
    sa += __shfl_xor(sa, m, 64);
    sb += __shfl_xor(sb, m, 64);
  }
  float inva = 1.0f / fmaxf(sqrtf(sa), 1e-12f);
  float invb = 1.0f / fmaxf(sqrtf(sb), 1e-12f);

  float zi0 = a.x * inva, zi1 = a.y * inva;
  float zj0 = b.x * invb, zj1 = b.y * invb;

  // positive pair dot in unscaled fp32 (matches reference's fp32 einsum)
  float p = zi0 * zj0 + zi1 * zj1;
  #pragma unroll
  for (int m = 32; m; m >>= 1) p += __shfl_xor(p, m, 64);
  if (lane == 0) pos[gw] = p;

  __hip_bfloat162* zr_i = (__hip_bfloat162*)(z + (size_t)gw * DIMS);
  __hip_bfloat162* zr_j = (__hip_bfloat162*)(z + (size_t)(gw + BB) * DIMS);
  __hip_bfloat162 vi, vj;
  vi.x = __float2bfloat16(zi0 * ZSCALE); vi.y = __float2bfloat16(zi1 * ZSCALE);
  vj.x = __float2bfloat16(zj0 * ZSCALE); vj.y = __float2bfloat16(zj1 * ZSCALE);
  zr_i[lane] = vi;
  zr_j[lane] = vj;
}

// ---------------------------------------------------------------------------
// Kernel 2: fused sim-GEMM + exp2 + row-sum. (R2 structure, VERIFIED VGPR=108
// with A-fragments genuinely resident — the only config that achieved that.)
// Block = 256 threads (4 waves), owns 256 rows x 512 columns.
// Each wave pins 64 rows of A (16 short8 = 64 VGPRs) for the whole kernel;
// each B-fragment ds_read_b128 feeds 4 MFMAs. 64-col chunks staged in LDS
// (17408 B, +8 pad per row -> 0 bank conflicts, measured R2).
// ONE change vs R2: __launch_bounds__(256,4) -> 4 blocks/CU (16 waves/CU),
// budget 128 VGPRs >= the 108 this kernel needs, so staging of one block
// hides under compute of the other three.
// MFMA 16x16x32 bf16: A[m=lane&15][k=quad*8+j], B[k=quad*8+j][n=lane&15],
// C: col=lane&15, row=quad*4+reg (HW-verified layouts).
// Diagonal included, subtracted in finalize.
// ---------------------------------------------------------------------------
__global__ __launch_bounds__(256, 4) void simloss_main(
    const __hip_bfloat16* __restrict__ z, float* __restrict__ denom) {
  const int blk      = blockIdx.x;
  const int rowBlk   = blk >> 4;       // 0..31
  const int colBlk   = blk & 15;       // 0..15
  const int rowBase  = rowBlk * ROWS_PER_BLOCK;
  const int colBase0 = colBlk * COLS_PER_BLOCK;
  const int tid  = threadIdx.x;
  const int wave = tid >> 6;
  const int lane = tid & 63;
  const int lr   = lane & 15;          // A-row / B-col / C-col within tile
  const int quad = lane >> 4;          // k-group for A/B, row-group for C

  __shared__ short lds[CHUNK * LDS_ROWW];  // 64 x 136 bf16 = 17408 B

  const ushort* zp = (const ushort*)z;

  // Preload A fragments: row = rowBase + wave*64 + rt*16 + lr, k = quad*8 + j
  short8 afrag[ROWTILES][4];
  #pragma unroll
  for (int rt = 0; rt < ROWTILES; rt++) {
    const int arow = rowBase + wave * ROWS_PER_WAVE + rt * 16 + lr;
    const short8* ap = (const short8*)(zp + (size_t)arow * DIMS + quad * 8);
    afrag[rt][0] = ap[0];
    afrag[rt][1] = ap[4];   // +32 shorts (k += 32)
    afrag[rt][2] = ap[8];
    afrag[rt][3] = ap[12];
  }

  float rowsum[ROWTILES][4];
  #pragma unroll
  for (int rt = 0; rt < ROWTILES; rt++)
    #pragma unroll
    for (int r = 0; r < 4; r++) rowsum[rt][r] = 0.0f;

  for (int cc = 0; cc < COLS_PER_BLOCK; cc += CHUNK) {
    const int colBase = colBase0 + cc;

    __syncthreads();  // previous iteration's LDS reads done
    {
      // Stage 64 cols x 128 dims of z: 1024 short8 total, 4 per thread.
      const short8* src = (const short8*)(zp + (size_t)colBase * DIMS);
      #pragma unroll
      for (int i = 0; i < 4; i++) {
        int idx  = tid + 256 * i;        // linear short8 index
        int row  = idx >> 4;             // 16 short8 per logical row
        int col8 = idx & 15;
        *(short8*)&lds[row * LDS_ROWW + col8 * 8] = src[idx];
      }
    }
    __syncthreads();

    #pragma unroll
    for (int t = 0; t < 4; t++) {  // 4 column tiles of 16
      const short8* bp = (const short8*)&lds[(t * 16 + lr) * LDS_ROWW + quad * 8];
      short8 b0 = bp[0];
      short8 b1 = bp[4];
      short8 b2 = bp[8];
      short8 b3 = bp[12];
      #pragma unroll
      for (int rt = 0; rt < ROWTILES; rt++) {
        float4v acc = {0.0f, 0.0f, 0.0f, 0.0f};
        acc = __builtin_amdgcn_mfma_f32_16x16x32_bf16(afrag[rt][0], b0, acc, 0, 0, 0);
        acc = __builtin_amdgcn_mfma_f32_16x16x32_bf16(afrag[rt][1], b1, acc, 0, 0, 0);
        acc = __builtin_amdgcn_mfma_f32_16x16x32_bf16(afrag[rt][2], b2, acc, 0, 0, 0);
        acc = __builtin_amdgcn_mfma_f32_16x16x32_bf16(afrag[rt][3], b3, acc, 0, 0, 0);
        // exp(sim/T) = exp2(acc) thanks to ZSCALE pre-scaling.
        #pragma unroll
        for (int r = 0; r < 4; r++)
          rowsum[rt][r] += __builtin_amdgcn_exp2f(acc[r]);
      }
    }
  }

  // Reduce partial row sums across the 16 lanes of each quad (xor bits 0..3).
  #pragma unroll
  for (int m = 1; m < 16; m <<= 1) {
    #pragma unroll
    for (int rt = 0; rt < ROWTILES; rt++)
      #pragma unroll
      for (int r = 0; r < 4; r++)
        rowsum[rt][r] += __shfl_xor(rowsum[rt][r], m, 64);
  }
  if (lr == 0) {
    #pragma unroll
    for (int rt = 0; rt < ROWTILES; rt++)
      #pragma unroll
      for (int r = 0; r < 4; r++)
        atomicAdd(&denom[rowBase + wave * ROWS_PER_WAVE + rt * 16 + quad * 4 + r],
                  rowsum[rt][r]);
  }
}

// ---------------------------------------------------------------------------
// Kernel 3: loss = (1/2B) * sum_r [ log(denom[r] - e^2) - 2*pos[r mod B] ]
// Single block; double accumulation (fp32 naive sum of 8192 ~9-magnitude
// terms would random-walk too close to the threshold).
// ---------------------------------------------------------------------------
__global__ __launch_bounds__(256) void finalize(
    const float* __restrict__ denom, const float* __restrict__ pos,
    float* __restrict__ out) {
  __shared__ double sred[256];
  int tid = threadIdx.x;
  double acc = 0.0;
  for (int r = tid; r < N2; r += 256) {
    acc += (double)(logf(denom[r] - DIAG_E2) - 2.0f * pos[r & (BB - 1)]);
  }
  sred[tid] = acc;
  __syncthreads();
  for (int s = 128; s; s >>= 1) {
    if (tid < s) sred[tid] += sred[tid + s];
    __syncthreads();
  }
  if (tid == 0) out[0] = (float)(sred[0] / (double)N2);
}

// ---------------------------------------------------------------------------
extern "C" void kernel_launch(void* const* d_in, const int* in_sizes, int n_in,
                              void* d_out, int out_size, void* d_ws, size_t ws_size,
                              hipStream_t stream) {
  const float* emb_i = (const float*)d_in[0];
  const float* emb_j = (const float*)d_in[1];

  // workspace layout
  __hip_bfloat16* z = (__hip_bfloat16*)d_ws;                       // 2 MiB
  float* pos   = (float*)((char*)d_ws + (size_t)N2 * DIMS * 2);    // 4096 f32
  float* denom = (float*)((char*)pos + BB * sizeof(float));        // 8192 f32

  norm_kernel<<<BB / 4, 256, 0, stream>>>(emb_i, emb_j, z, pos, denom);
  simloss_main<<<(N2 / ROWS_PER_BLOCK) * COL_SPLIT, 256, 0, stream>>>(z, denom);
  finalize<<<1, 256, 0, stream>>>(denom, pos, (float*)d_out);
}

// Round 7
// 94.802 us; speedup vs baseline: 2.0963x; 1.3150x over previous
//
#include <hip/hip_runtime.h>
#include <hip/hip_bf16.h>
#include <math.h>

// Problem constants (B=4096, D=128, T=0.5 -> 1/T = 2)
#define BB       4096
#define N2       8192          // 2B rows of z
#define DIMS     128
#define WAVES    4
#define ROWTILES 4             // 16-row MFMA tiles per wave
#define ROWS_PER_WAVE   64     // ROWTILES * 16
#define ROWS_PER_BLOCK  256    // WAVES * ROWS_PER_WAVE
#define COL_SPLIT       32     // R7: 16 -> 32 (grid 1024 = 4 blocks/CU dispatched)
#define COLS_PER_BLOCK  (N2 / COL_SPLIT)   // 256
#define CHUNK    64            // columns staged in LDS per iteration
#define LDS_PAD  8             // bf16 pad per row: breaks 256B-stride conflicts
#define LDS_ROWW (DIMS + LDS_PAD)  // 136 shorts = 272 B

// z rows pre-scaled by ZSCALE so the MFMA dot yields sim * 2*log2(e),
// i.e. exp(sim/T) = exp2(acc). ZSCALE^2 = 2*log2(e) = 2.8853900818.
#define ZSCALE   1.6986436f
// diagonal term exp(2*|z_r|^2) ~= e^2 — included in denom, subtracted in finalize.
#define DIAG_E2  7.38905609893065f

typedef __attribute__((ext_vector_type(8))) short short8;   // 8 x bf16 (4 VGPRs)
typedef __attribute__((ext_vector_type(4))) float float4v;  // MFMA C/D

// ---------------------------------------------------------------------------
// Kernel 1: normalize rows (fp32), positives (fp32), write z bf16 * ZSCALE.
// Also zeroes denom (blocks 0..31). One wave per row-pair r.
// ---------------------------------------------------------------------------
__global__ __launch_bounds__(256) void norm_kernel(
    const float* __restrict__ emb_i, const float* __restrict__ emb_j,
    __hip_bfloat16* __restrict__ z, float* __restrict__ pos,
    float* __restrict__ denom) {
  if (blockIdx.x < N2 / 256) denom[blockIdx.x * 256 + threadIdx.x] = 0.0f;

  int gw   = (blockIdx.x * blockDim.x + threadIdx.x) >> 6;  // row pair
  int lane = threadIdx.x & 63;
  if (gw >= BB) return;

  const float2* ei = (const float2*)(emb_i + (size_t)gw * DIMS);
  const float2* ej = (const float2*)(emb_j + (size_t)gw * DIMS);
  float2 a = ei[lane];
  float2 b = ej[lane];

  float sa = a.x * a.x + a.y * a.y;
  float sb = b.x * b.x + b.y * b.y;
  #pragma unroll
  for (int m = 32; m; m >>= 1) {
    sa += __shfl_xor(sa, m, 64);
    sb += __shfl_xor(sb, m, 64);
  }
  float inva = 1.0f / fmaxf(sqrtf(sa), 1e-12f);
  float invb = 1.0f / fmaxf(sqrtf(sb), 1e-12f);

  float zi0 = a.x * inva, zi1 = a.y * inva;
  float zj0 = b.x * invb, zj1 = b.y * invb;

  // positive pair dot in unscaled fp32 (matches reference's fp32 einsum)
  float p = zi0 * zj0 + zi1 * zj1;
  #pragma unroll
  for (int m = 32; m; m >>= 1) p += __shfl_xor(p, m, 64);
  if (lane == 0) pos[gw] = p;

  __hip_bfloat162* zr_i = (__hip_bfloat162*)(z + (size_t)gw * DIMS);
  __hip_bfloat162* zr_j = (__hip_bfloat162*)(z + (size_t)(gw + BB) * DIMS);
  __hip_bfloat162 vi, vj;
  vi.x = __float2bfloat16(zi0 * ZSCALE); vi.y = __float2bfloat16(zi1 * ZSCALE);
  vj.x = __float2bfloat16(zj0 * ZSCALE); vj.y = __float2bfloat16(zj1 * ZSCALE);
  zr_i[lane] = vi;
  zr_j[lane] = vj;
}

// ---------------------------------------------------------------------------
// Kernel 2: fused sim-GEMM + exp2 + row-sum. EXACT R2 structure.
// __launch_bounds__(256,2): the ONLY config where the compiler keeps the
// A-fragments resident (VGPR=108). (256,4) twice forced VGPR<=64 + scratch
// spill (R4: 60, R6: 64 + 84MB scratch writes) — do not revisit.
// At VGPR=108 the HW fits 4 waves/SIMD anyway, so runtime occupancy is
// 4 blocks/CU provided the GRID supplies them — which is the one R7 change:
// COL_SPLIT 16->32 makes grid 1024 = 4 blocks/CU dispatched, doubling
// waves/CU to 16 so staging barriers of one block hide under the other
// three blocks' MFMA/exp2 (m114 overlap).
// Block = 256 threads (4 waves), owns 256 rows x 256 columns.
// Each wave pins 64 rows of A (16 short8 = 64 VGPRs); each B ds_read_b128
// feeds 4 MFMAs. 64-col chunks staged in LDS (17408 B, +8 pad, 0 conflicts).
// MFMA 16x16x32 bf16: A[m=lane&15][k=quad*8+j], B[k=quad*8+j][n=lane&15],
// C: col=lane&15, row=quad*4+reg (HW-verified layouts).
// Diagonal included, subtracted in finalize.
// ---------------------------------------------------------------------------
__global__ __launch_bounds__(256, 2) void simloss_main(
    const __hip_bfloat16* __restrict__ z, float* __restrict__ denom) {
  const int blk      = blockIdx.x;
  const int rowBlk   = blk >> 5;       // 0..31 (32 row-blocks)
  const int colBlk   = blk & 31;       // 0..31 (32 col-blocks)
  const int rowBase  = rowBlk * ROWS_PER_BLOCK;
  const int colBase0 = colBlk * COLS_PER_BLOCK;
  const int tid  = threadIdx.x;
  const int wave = tid >> 6;
  const int lane = tid & 63;
  const int lr   = lane & 15;          // A-row / B-col / C-col within tile
  const int quad = lane >> 4;          // k-group for A/B, row-group for C

  __shared__ short lds[CHUNK * LDS_ROWW];  // 64 x 136 bf16 = 17408 B

  const ushort* zp = (const ushort*)z;

  // Preload A fragments: row = rowBase + wave*64 + rt*16 + lr, k = quad*8 + j
  short8 afrag[ROWTILES][4];
  #pragma unroll
  for (int rt = 0; rt < ROWTILES; rt++) {
    const int arow = rowBase + wave * ROWS_PER_WAVE + rt * 16 + lr;
    const short8* ap = (const short8*)(zp + (size_t)arow * DIMS + quad * 8);
    afrag[rt][0] = ap[0];
    afrag[rt][1] = ap[4];   // +32 shorts (k += 32)
    afrag[rt][2] = ap[8];
    afrag[rt][3] = ap[12];
  }

  float rowsum[ROWTILES][4];
  #pragma unroll
  for (int rt = 0; rt < ROWTILES; rt++)
    #pragma unroll
    for (int r = 0; r < 4; r++) rowsum[rt][r] = 0.0f;

  for (int cc = 0; cc < COLS_PER_BLOCK; cc += CHUNK) {
    const int colBase = colBase0 + cc;

    __syncthreads();  // previous iteration's LDS reads done
    {
      // Stage 64 cols x 128 dims of z: 1024 short8 total, 4 per thread.
      const short8* src = (const short8*)(zp + (size_t)colBase * DIMS);
      #pragma unroll
      for (int i = 0; i < 4; i++) {
        int idx  = tid + 256 * i;        // linear short8 index
        int row  = idx >> 4;             // 16 short8 per logical row
        int col8 = idx & 15;
        *(short8*)&lds[row * LDS_ROWW + col8 * 8] = src[idx];
      }
    }
    __syncthreads();

    #pragma unroll
    for (int t = 0; t < 4; t++) {  // 4 column tiles of 16
      const short8* bp = (const short8*)&lds[(t * 16 + lr) * LDS_ROWW + quad * 8];
      short8 b0 = bp[0];
      short8 b1 = bp[4];
      short8 b2 = bp[8];
      short8 b3 = bp[12];
      #pragma unroll
      for (int rt = 0; rt < ROWTILES; rt++) {
        float4v acc = {0.0f, 0.0f, 0.0f, 0.0f};
        acc = __builtin_amdgcn_mfma_f32_16x16x32_bf16(afrag[rt][0], b0, acc, 0, 0, 0);
        acc = __builtin_amdgcn_mfma_f32_16x16x32_bf16(afrag[rt][1], b1, acc, 0, 0, 0);
        acc = __builtin_amdgcn_mfma_f32_16x16x32_bf16(afrag[rt][2], b2, acc, 0, 0, 0);
        acc = __builtin_amdgcn_mfma_f32_16x16x32_bf16(afrag[rt][3], b3, acc, 0, 0, 0);
        // exp(sim/T) = exp2(acc) thanks to ZSCALE pre-scaling.
        #pragma unroll
        for (int r = 0; r < 4; r++)
          rowsum[rt][r] += __builtin_amdgcn_exp2f(acc[r]);
      }
    }
  }

  // Reduce partial row sums across the 16 lanes of each quad (xor bits 0..3).
  #pragma unroll
  for (int m = 1; m < 16; m <<= 1) {
    #pragma unroll
    for (int rt = 0; rt < ROWTILES; rt++)
      #pragma unroll
      for (int r = 0; r < 4; r++)
        rowsum[rt][r] += __shfl_xor(rowsum[rt][r], m, 64);
  }
  if (lr == 0) {
    #pragma unroll
    for (int rt = 0; rt < ROWTILES; rt++)
      #pragma unroll
      for (int r = 0; r < 4; r++)
        atomicAdd(&denom[rowBase + wave * ROWS_PER_WAVE + rt * 16 + quad * 4 + r],
                  rowsum[rt][r]);
  }
}

// ---------------------------------------------------------------------------
// Kernel 3: loss = (1/2B) * sum_r [ log(denom[r] - e^2) - 2*pos[r mod B] ]
// Single block; double accumulation (fp32 naive sum of 8192 ~9-magnitude
// terms would random-walk too close to the threshold).
// ---------------------------------------------------------------------------
__global__ __launch_bounds__(256) void finalize(
    const float* __restrict__ denom, const float* __restrict__ pos,
    float* __restrict__ out) {
  __shared__ double sred[256];
  int tid = threadIdx.x;
  double acc = 0.0;
  for (int r = tid; r < N2; r += 256) {
    acc += (double)(logf(denom[r] - DIAG_E2) - 2.0f * pos[r & (BB - 1)]);
  }
  sred[tid] = acc;
  __syncthreads();
  for (int s = 128; s; s >>= 1) {
    if (tid < s) sred[tid] += sred[tid + s];
    __syncthreads();
  }
  if (tid == 0) out[0] = (float)(sred[0] / (double)N2);
}

// ---------------------------------------------------------------------------
extern "C" void kernel_launch(void* const* d_in, const int* in_sizes, int n_in,
                              void* d_out, int out_size, void* d_ws, size_t ws_size,
                              hipStream_t stream) {
  const float* emb_i = (const float*)d_in[0];
  const float* emb_j = (const float*)d_in[1];

  // workspace layout
  __hip_bfloat16* z = (__hip_bfloat16*)d_ws;                       // 2 MiB
  float* pos   = (float*)((char*)d_ws + (size_t)N2 * DIMS * 2);    // 4096 f32
  float* denom = (float*)((char*)pos + BB * sizeof(float));        // 8192 f32

  norm_kernel<<<BB / 4, 256, 0, stream>>>(emb_i, emb_j, z, pos, denom);
  simloss_main<<<(N2 / ROWS_PER_BLOCK) * COL_SPLIT, 256, 0, stream>>>(z, denom);
  finalize<<<1, 256, 0, stream>>>(denom, pos, (float*)d_out);
}